// Round 1
// baseline (72.196 us; speedup 1.0000x reference)
//
#include <hip/hip_runtime.h>

typedef __attribute__((ext_vector_type(4))) float f32x4;
typedef __attribute__((ext_vector_type(8))) short short8;
typedef __attribute__((ext_vector_type(8))) __bf16 bf16x8;

constexpr int kN = 4096;
constexpr int kF = 256;
constexpr int kH = 4;
constexpr int kD = 64;
constexpr float kLog2e = 1.4426950408889634f;

__device__ __forceinline__ unsigned short f2us(float x) {
  __bf16 b = (__bf16)x;
  return __builtin_bit_cast(unsigned short, b);
}

// ---------------------------------------------------------------------------
// kA: wa[h][i] = sum_d W[h][i][d] * a[h][d]   (folds a into W so s_src/s_dst
// become exact fp32 GEMVs against h, no fp32 Wh needed)
// ---------------------------------------------------------------------------
__global__ __launch_bounds__(256) void k_wa(const float* __restrict__ W,
                                            const float* __restrict__ a_src,
                                            const float* __restrict__ a_dst,
                                            float* __restrict__ wa_src,
                                            float* __restrict__ wa_dst) {
  const int h = blockIdx.x, i = threadIdx.x;
  __shared__ float as[kD], ad[kD];
  if (i < kD) { as[i] = a_src[h * kD + i]; ad[i] = a_dst[h * kD + i]; }
  __syncthreads();
  const float* w = W + ((size_t)h * kF + i) * kD;
  float ss = 0.f, sd = 0.f;
#pragma unroll
  for (int d = 0; d < kD; d++) { const float wv = w[d]; ss += wv * as[d]; sd += wv * ad[d]; }
  wa_src[h * kF + i] = ss;
  wa_dst[h * kF + i] = sd;
}

// ---------------------------------------------------------------------------
// k_wh: Whb[h] = bf16( h @ W[h] ) via MFMA 16x16x32, stored PRE-SWIZZLED in
// B-fragment order: frag_id = ((h*128 + mstep)*4 + dt)*64 + lane, 8 bf16/lane.
// B layout: col j = lane&15 (d), k = 8*(lane>>4)+e (m within 32-row step).
// ---------------------------------------------------------------------------
__global__ __launch_bounds__(256) void k_wh(const float* __restrict__ hmat,
                                            const float* __restrict__ W,
                                            unsigned short* __restrict__ whb) {
  const int h = blockIdx.x & 3, rb = blockIdx.x >> 2;
  const int row0 = rb * 64;
  __shared__ unsigned short wlds[16384];  // W[h] as swizzled bf16 frags
  const int t = threadIdx.x;
  {
    const int d = t & 63;
    const int dt = d >> 4, dl = d & 15;
    for (int kb = 0; kb < 64; kb++) {
      const int k = kb * 4 + (t >> 6);
      const float wv = W[((size_t)h * kF + k) * kD + d];
      const int ks = k >> 5, kl = k & 31;
      const int lane2 = ((kl >> 3) << 4) | dl;
      const int e = kl & 7;
      wlds[(((ks * 4 + dt) * 64 + lane2) << 3) + e] = f2us(wv);
    }
  }
  __syncthreads();
  const int wave = t >> 6, lane = t & 63;
  const int lr = lane & 15, lg = lane >> 4;
  const int nrow = row0 + wave * 16 + lr;
  f32x4 acc[4] = {};
  const float* hrow = hmat + (size_t)nrow * kF + 8 * lg;
#pragma unroll
  for (int ks = 0; ks < 8; ks++) {
    const f32x4 h0 = *reinterpret_cast<const f32x4*>(hrow + ks * 32);
    const f32x4 h1 = *reinterpret_cast<const f32x4*>(hrow + ks * 32 + 4);
    bf16x8 af;
#pragma unroll
    for (int j = 0; j < 4; j++) { af[j] = (__bf16)h0[j]; af[4 + j] = (__bf16)h1[j]; }
#pragma unroll
    for (int dt = 0; dt < 4; dt++) {
      const short8 bs = *reinterpret_cast<const short8*>(wlds + (((ks * 4 + dt) * 64 + lane) << 3));
      acc[dt] = __builtin_amdgcn_mfma_f32_16x16x32_bf16(af, __builtin_bit_cast(bf16x8, bs), acc[dt], 0, 0, 0);
    }
  }
  // C layout: row n = 4*lg + r (tile-rel), col d = dt*16 + lr -> scatter to frag order
#pragma unroll
  for (int dt = 0; dt < 4; dt++) {
#pragma unroll
    for (int r = 0; r < 4; r++) {
      const int n = row0 + wave * 16 + lg * 4 + r;
      const int mstep = n >> 5, kl = n & 31;
      const int lane2 = ((kl >> 3) << 4) | lr;
      const int e = kl & 7;
      whb[((((size_t)(h * 128 + mstep) * 4 + dt) * 64 + lane2) << 3) + e] = f2us(acc[dt][r]);
    }
  }
}

// ---------------------------------------------------------------------------
// k_s: s_src[h][n] = h[n,:]·wa_src[h,:]  (exact fp32, one wave per row)
// ---------------------------------------------------------------------------
__global__ __launch_bounds__(256) void k_s(const float* __restrict__ hmat,
                                           const float* __restrict__ wa_src,
                                           const float* __restrict__ wa_dst,
                                           float* __restrict__ s_src,
                                           float* __restrict__ s_dst) {
  const int wave = threadIdx.x >> 6, lane = threadIdx.x & 63;
  const int n = blockIdx.x * 4 + wave;
  const f32x4 hv = reinterpret_cast<const f32x4*>(hmat + (size_t)n * kF)[lane];
#pragma unroll
  for (int h = 0; h < kH; h++) {
    const f32x4 sv = reinterpret_cast<const f32x4*>(wa_src + h * kF)[lane];
    const f32x4 dv = reinterpret_cast<const f32x4*>(wa_dst + h * kF)[lane];
    float as = hv[0] * sv[0] + hv[1] * sv[1] + hv[2] * sv[2] + hv[3] * sv[3];
    float ad = hv[0] * dv[0] + hv[1] * dv[1] + hv[2] * dv[2] + hv[3] * dv[3];
#pragma unroll
    for (int off = 32; off > 0; off >>= 1) {
      as += __shfl_xor(as, off);
      ad += __shfl_xor(ad, off);
    }
    if (lane == 0) { s_src[h * kN + n] = as; s_dst[h * kN + n] = ad; }
  }
}

// ---------------------------------------------------------------------------
// k_max: M[h] = max_n s_dst[h][n]  (upper bound for every masked row max)
// ---------------------------------------------------------------------------
__global__ __launch_bounds__(256) void k_max(const float* __restrict__ s_dst,
                                             float* __restrict__ Mh) {
  const int h = blockIdx.x, t = threadIdx.x;
  float m = -1e30f;
  for (int n = t; n < kN; n += 256) m = fmaxf(m, s_dst[h * kN + n]);
  __shared__ float red[256];
  red[t] = m;
  __syncthreads();
#pragma unroll
  for (int s = 128; s > 0; s >>= 1) {
    if (t < s) red[t] = fmaxf(red[t], red[t + s]);
    __syncthreads();
  }
  if (t == 0) Mh[h] = red[0];
}

// p-generation: arg = (lrelu(s_src+sd) - bound)*log2e = max(u+c1, v+c2);
// p = adj * exp2(arg)  (adj is exactly 0.0/1.0)
__device__ __forceinline__ bf16x8 make_p(const f32x4 u0, const f32x4 u1,
                                         const f32x4 v0, const f32x4 v1,
                                         const float cc1, const float cc2,
                                         const f32x4 aa, const f32x4 ab) {
  bf16x8 r;
#pragma unroll
  for (int j = 0; j < 4; j++) {
    const float arg = fmaxf(u0[j] + cc1, v0[j] + cc2);
    r[j] = (__bf16)(aa[j] * __builtin_amdgcn_exp2f(arg));
  }
#pragma unroll
  for (int j = 0; j < 4; j++) {
    const float arg = fmaxf(u1[j] + cc1, v1[j] + cc2);
    r[4 + j] = (__bf16)(ab[j] * __builtin_amdgcn_exp2f(arg));
  }
  return r;
}

// ---------------------------------------------------------------------------
// k_attn: fused mask+softmax-numerator+PV. 256 blocks = 128 row-groups x 2
// col-splits; 8 waves = 4 heads x 2 col-interleaves; BQ=32 rows/block.
// Writes partial (acc, Z) per col-split; fixed per-row bound -> partials add.
// Z via MFMA against all-ones B fragment (keeps it off the VALU).
// ---------------------------------------------------------------------------
__global__ __launch_bounds__(512, 2) void k_attn(const float* __restrict__ adj,
                                                 const unsigned short* __restrict__ whb,
                                                 const float* __restrict__ s_src,
                                                 const float* __restrict__ s_dst,
                                                 const float* __restrict__ Mh,
                                                 float* __restrict__ accP,
                                                 float* __restrict__ zP) {
  const int bid = blockIdx.x;
  const int rb = bid >> 1, cs = bid & 1;
  const int row0 = rb * 32;
  const int colbase = cs * 2048;
  const int t = threadIdx.x;
  const int wave = t >> 6, lane = t & 63;
  const int h = wave & 3, q = wave >> 2;
  const int lr = lane & 15, lg = lane >> 4;

  __shared__ float sdl[4 * 2048];  // staged s_dst slice; reused for acc combine
  __shared__ float zx[4][32];

  {
    const int base = colbase + t * 4;
#pragma unroll
    for (int hh = 0; hh < 4; hh++) {
      const f32x4 v = *reinterpret_cast<const f32x4*>(s_dst + hh * kN + base);
      *reinterpret_cast<f32x4*>(sdl + hh * 2048 + t * 4) = v;
    }
  }
  __syncthreads();

  const float M = Mh[h];
  float c1[2], c2[2];
#pragma unroll
  for (int rt = 0; rt < 2; rt++) {
    const float A = s_src[h * kN + row0 + rt * 16 + lr];
    const float xb = A + M;
    const float B = fmaxf(xb, 0.2f * xb);  // lrelu at the global-max bound
    c1[rt] = (A - B) * kLog2e;
    c2[rt] = (0.2f * A - B) * kLog2e;
  }

  f32x4 acc[2][4] = {};
  f32x4 accz[2] = {};
  bf16x8 ones;
#pragma unroll
  for (int e = 0; e < 8; e++) ones[e] = (__bf16)1.0f;

  const float* ap0 = adj + (size_t)(row0 + lr) * kN + colbase + q * 32 + 8 * lg;
  const float* ap1 = ap0 + (size_t)16 * kN;
  const float* sdp = sdl + h * 2048 + q * 32 + 8 * lg;
  const short8* wb = reinterpret_cast<const short8*>(whb) + (size_t)h * 32768 + lane;
  const int mstep0 = cs * 64 + q;

  // prefetch it=0 adjacency
  f32x4 adj0a = *reinterpret_cast<const f32x4*>(ap0);
  f32x4 adj0b = *reinterpret_cast<const f32x4*>(ap0 + 4);
  f32x4 adj1a = *reinterpret_cast<const f32x4*>(ap1);
  f32x4 adj1b = *reinterpret_cast<const f32x4*>(ap1 + 4);

  for (int it = 0; it < 32; it++) {
    const f32x4 c0a = adj0a, c0b = adj0b, c1a = adj1a, c1b = adj1b;
    if (it < 31) {  // prefetch next iteration's adj tile (HBM latency hiding)
      const float* np0 = ap0 + (it + 1) * 64;
      const float* np1 = ap1 + (it + 1) * 64;
      adj0a = *reinterpret_cast<const f32x4*>(np0);
      adj0b = *reinterpret_cast<const f32x4*>(np0 + 4);
      adj1a = *reinterpret_cast<const f32x4*>(np1);
      adj1b = *reinterpret_cast<const f32x4*>(np1 + 4);
    }
    const float* sp = sdp + it * 64;
    const f32x4 sd0 = *reinterpret_cast<const f32x4*>(sp);
    const f32x4 sd1 = *reinterpret_cast<const f32x4*>(sp + 4);

    const short8* wbb = wb + (size_t)(mstep0 + it * 2) * 256;
    const short8 b0s = wbb[0];
    const short8 b1s = wbb[64];
    const short8 b2s = wbb[128];
    const short8 b3s = wbb[192];

    const f32x4 u0 = sd0 * kLog2e, u1 = sd1 * kLog2e;
    const f32x4 v0 = sd0 * (0.2f * kLog2e), v1 = sd1 * (0.2f * kLog2e);

    const bf16x8 P0 = make_p(u0, u1, v0, v1, c1[0], c2[0], c0a, c0b);
    const bf16x8 P1 = make_p(u0, u1, v0, v1, c1[1], c2[1], c1a, c1b);
    const bf16x8 B0 = __builtin_bit_cast(bf16x8, b0s);
    const bf16x8 B1 = __builtin_bit_cast(bf16x8, b1s);
    const bf16x8 B2 = __builtin_bit_cast(bf16x8, b2s);
    const bf16x8 B3 = __builtin_bit_cast(bf16x8, b3s);

    acc[0][0] = __builtin_amdgcn_mfma_f32_16x16x32_bf16(P0, B0, acc[0][0], 0, 0, 0);
    acc[0][1] = __builtin_amdgcn_mfma_f32_16x16x32_bf16(P0, B1, acc[0][1], 0, 0, 0);
    acc[0][2] = __builtin_amdgcn_mfma_f32_16x16x32_bf16(P0, B2, acc[0][2], 0, 0, 0);
    acc[0][3] = __builtin_amdgcn_mfma_f32_16x16x32_bf16(P0, B3, acc[0][3], 0, 0, 0);
    accz[0]   = __builtin_amdgcn_mfma_f32_16x16x32_bf16(P0, ones, accz[0], 0, 0, 0);
    acc[1][0] = __builtin_amdgcn_mfma_f32_16x16x32_bf16(P1, B0, acc[1][0], 0, 0, 0);
    acc[1][1] = __builtin_amdgcn_mfma_f32_16x16x32_bf16(P1, B1, acc[1][1], 0, 0, 0);
    acc[1][2] = __builtin_amdgcn_mfma_f32_16x16x32_bf16(P1, B2, acc[1][2], 0, 0, 0);
    acc[1][3] = __builtin_amdgcn_mfma_f32_16x16x32_bf16(P1, B3, acc[1][3], 0, 0, 0);
    accz[1]   = __builtin_amdgcn_mfma_f32_16x16x32_bf16(P1, ones, accz[1], 0, 0, 0);
  }

  __syncthreads();  // done reading sdl; reuse it for acc exchange
  if (q == 1) {
    float* dst = sdl + h * 2048;
#pragma unroll
    for (int rt = 0; rt < 2; rt++)
#pragma unroll
      for (int dt = 0; dt < 4; dt++)
        *reinterpret_cast<f32x4*>(dst + ((rt * 4 + dt) * 64 + lane) * 4) = acc[rt][dt];
    if (lr == 0) {
#pragma unroll
      for (int rt = 0; rt < 2; rt++)
#pragma unroll
        for (int r = 0; r < 4; r++) zx[h][rt * 16 + lg * 4 + r] = accz[rt][r];
    }
  }
  __syncthreads();
  if (q == 0) {
    const float* src = sdl + h * 2048;
#pragma unroll
    for (int rt = 0; rt < 2; rt++)
#pragma unroll
      for (int dt = 0; dt < 4; dt++) {
        const f32x4 o = *reinterpret_cast<const f32x4*>(src + ((rt * 4 + dt) * 64 + lane) * 4);
        acc[rt][dt] += o;
      }
    const size_t obase = ((size_t)(cs * 4 + h) * kN) * 64;
#pragma unroll
    for (int rt = 0; rt < 2; rt++)
#pragma unroll
      for (int dt = 0; dt < 4; dt++)
#pragma unroll
        for (int r = 0; r < 4; r++) {
          const int n = row0 + rt * 16 + lg * 4 + r;
          const int d = dt * 16 + lr;
          accP[obase + (size_t)n * 64 + d] = acc[rt][dt][r];
        }
#pragma unroll
    for (int rt = 0; rt < 2; rt++)
#pragma unroll
      for (int r = 0; r < 4; r++) {
        const float z = accz[rt][r] + zx[h][rt * 16 + lg * 4 + r];
        if (lr == 0)
          zP[(size_t)(cs * 4 + h) * kN + row0 + rt * 16 + lg * 4 + r] = z;
      }
  }
}

// ---------------------------------------------------------------------------
// k_fin: out[n][h*64+d] = elu( (acc0+acc1) / (z0+z1) )
// ---------------------------------------------------------------------------
__global__ __launch_bounds__(256) void k_fin(const float* __restrict__ accP,
                                             const float* __restrict__ zP,
                                             float* __restrict__ out) {
  const int idx = blockIdx.x * 256 + threadIdx.x;  // 262144 float4s
  const int d4 = idx & 15;
  const int hh = (idx >> 4) & 3;
  const int n = idx >> 6;
  const f32x4* a0 = reinterpret_cast<const f32x4*>(accP) + ((size_t)hh * kN + n) * 16 + d4;
  const f32x4* a1 = a0 + (size_t)4 * kN * 16;
  f32x4 v = *a0 + *a1;
  const float z = zP[hh * kN + n] + zP[(4 + hh) * kN + n];
  const float rz = 1.0f / z;
  f32x4 o;
#pragma unroll
  for (int j = 0; j < 4; j++) {
    const float x = v[j] * rz;
    o[j] = x > 0.0f ? x : (__builtin_amdgcn_exp2f(x * kLog2e) - 1.0f);
  }
  reinterpret_cast<f32x4*>(out)[(size_t)n * 64 + hh * 16 + d4] = o;
}

extern "C" void kernel_launch(void* const* d_in, const int* in_sizes, int n_in,
                              void* d_out, int out_size, void* d_ws, size_t ws_size,
                              hipStream_t stream) {
  const float* hmat  = (const float*)d_in[0];
  const float* adj   = (const float*)d_in[1];
  const float* W     = (const float*)d_in[2];
  const float* a_src = (const float*)d_in[3];
  const float* a_dst = (const float*)d_in[4];
  float* out = (float*)d_out;

  char* ws = (char*)d_ws;
  unsigned short* whb = (unsigned short*)(ws);                    // 2 MB  (bf16 Wh, frag-swizzled)
  float* wa_src = (float*)(ws + (2u << 20));                      // 4 KB
  float* wa_dst = (float*)(ws + (2u << 20) + 4096);               // 4 KB
  float* s_src  = (float*)(ws + (2u << 20) + 8192);               // 64 KB
  float* s_dst  = (float*)(ws + (2u << 20) + 8192 + 65536);       // 64 KB
  float* Mh     = (float*)(ws + (2u << 20) + 8192 + 2 * 65536);   // 16 B
  float* accP   = (float*)(ws + (4u << 20));                      // 8 MB
  float* zP     = (float*)(ws + (12u << 20));                     // 128 KB

  hipLaunchKernelGGL(k_wa, dim3(4), dim3(256), 0, stream, W, a_src, a_dst, wa_src, wa_dst);
  hipLaunchKernelGGL(k_wh, dim3(256), dim3(256), 0, stream, hmat, W, whb);
  hipLaunchKernelGGL(k_s, dim3(1024), dim3(256), 0, stream, hmat, wa_src, wa_dst, s_src, s_dst);
  hipLaunchKernelGGL(k_max, dim3(4), dim3(256), 0, stream, s_dst, Mh);
  hipLaunchKernelGGL(k_attn, dim3(256), dim3(512), 0, stream, adj, whb, s_src, s_dst, Mh, accP, zP);
  hipLaunchKernelGGL(k_fin, dim3(1024), dim3(256), 0, stream, accP, zP, out);
}